// Round 11
// baseline (508.927 us; speedup 1.0000x reference)
//
#include <hip/hip_runtime.h>
#include <hip/hip_bf16.h>

// Problem constants (fixed by the reference)
#define VOCAB 50000
#define D     300
#define B_    64
#define LC    32
#define T_    256
#define LT    64
#define NSEL  5

// B table row: 1024 B, 128-line aligned:
//   [f16 hi x320 = 640 B][u8 e5m2-trunc lo x320 = 320 B][64 B zero pad]
#define TROWB  1024
// A image per batch (ws + LDS), 30976 B total:
//   hi: uint4[0..1280)  = 32 rows x 40 slots (16 B), slot s at s^(m&7) (swizzled)
//   lo: bytes [20480..30976) = 32 rows x 328 B (8 B per k-slot, 8 B pad/row)
#define A_HI_U4    1280
#define A_LO_OFF   20480
#define A_LO_STRIDE 328
#define A_IMG_BYTES 30976
#define A_IMG_U4    1936

typedef _Float16 half8_t __attribute__((ext_vector_type(8)));
typedef _Float16 half4_t __attribute__((ext_vector_type(4)));
typedef float    f32x4   __attribute__((ext_vector_type(4)));

// e5m2-style lo encode: rounded high byte of f16 bits (lo tiny -> no overflow)
__device__ __forceinline__ unsigned char enc_lo(float x, _Float16 h) {
    _Float16 l = (_Float16)(x - (float)h);
    unsigned short b = __builtin_bit_cast(unsigned short, l);
    return (unsigned char)((unsigned short)(b + 0x80) >> 8);
}

// decode 8 lo-bytes -> half8 (f16 = byte << 8)
__device__ __forceinline__ half8_t decode_lo8(uint2 w) {
    unsigned int a = w.x, b = w.y;
    unsigned int p0 = ((a & 0xFFu) << 8) | ((a & 0xFF00u) << 16);
    unsigned int p1 = ((a & 0xFF0000u) >> 8) | (a & 0xFF000000u);
    unsigned int p2 = ((b & 0xFFu) << 8) | ((b & 0xFF00u) << 16);
    unsigned int p3 = ((b & 0xFF0000u) >> 8) | (b & 0xFF000000u);
    uint4 r = make_uint4(p0, p1, p2, p3);
    return __builtin_bit_cast(half8_t, r);
}

// ---------------- K0: whole-table f16hi + u8lo conversion (1024 B rows) ------
__global__ __launch_bounds__(256) void k_prep_table(const float* __restrict__ emb,
                                                    unsigned char* __restrict__ tab) {
    int r = blockIdx.x * 4 + (threadIdx.x >> 6);     // 12500*4 = 50000 rows
    int lane = threadIdx.x & 63;
    const float* src = emb + (size_t)r * D;
    unsigned char* row = tab + (size_t)r * TROWB;
#pragma unroll
    for (int i = 0; i < 2; ++i) {
        int k4 = lane + i * 64;                      // float4 index < 80
        if (k4 >= 80) continue;
        float4 v = (k4 < 75) ? *(const float4*)(src + 4 * k4)
                             : make_float4(0.f, 0.f, 0.f, 0.f);
        _Float16 h0 = (_Float16)v.x, h1 = (_Float16)v.y;
        _Float16 h2 = (_Float16)v.z, h3 = (_Float16)v.w;
        half4_t hv; hv[0] = h0; hv[1] = h1; hv[2] = h2; hv[3] = h3;
        *(half4_t*)(row + 8 * k4) = hv;
        unsigned int lw = (unsigned int)enc_lo(v.x, h0)
                        | ((unsigned int)enc_lo(v.y, h1) << 8)
                        | ((unsigned int)enc_lo(v.z, h2) << 16)
                        | ((unsigned int)enc_lo(v.w, h3) << 24);
        *(unsigned int*)(row + 640 + 4 * k4) = lw;
    }
    if (lane < 4)                                    // zero the 64 B pad
        *(uint4*)(row + 960 + 16 * lane) = make_uint4(0, 0, 0, 0);
}

// ---------------- K1: claim -> packed hi/lo swizzled image in ws -------------
__global__ void k_prep_claim(const int* __restrict__ claim,
                             const float* __restrict__ emb,
                             unsigned char* __restrict__ wsA) {
    int row = blockIdx.x;                 // 0..B_*LC-1
    int b = row >> 5, m = row & 31;
    int tok = claim[row];
    const float* src = emb + (size_t)tok * D;
    unsigned char* base = wsA + (size_t)b * A_IMG_BYTES;
    _Float16* hbase = (_Float16*)base;
    for (int k = threadIdx.x; k < 320; k += 64) {
        float x = (k < D) ? src[k] : 0.0f;
        _Float16 h = (_Float16)x;
        int sp = ((k >> 3) ^ (m & 7));
        hbase[(m * 40 + sp) * 8 + (k & 7)] = h;
        base[A_LO_OFF + m * A_LO_STRIDE + (k >> 3) * 8 + (k & 7)] = enc_lo(x, h);
    }
}

// hi/lo split of a float4 pair into half8 hi and half8 lo (slow path only)
__device__ __forceinline__ void split8(const float4& a, const float4& b,
                                       half8_t& hv, half8_t& lv) {
    float x[8] = {a.x, a.y, a.z, a.w, b.x, b.y, b.z, b.w};
#pragma unroll
    for (int i = 0; i < 8; ++i) {
        _Float16 h = (_Float16)x[i];
        hv[i] = h;
        lv[i] = (_Float16)(x[i] - (float)h);
    }
}

// ---------------- shared K-loop: U tile via f16x2-split MFMA ------------------
// acc[mi][ni] covers c = mi*16+quad*4+reg, l = lcol0 + ni*16 + ln.
template<bool FAST, int NI>
__device__ __forceinline__ void compute_U(const uint4* sA,
                                          const float* __restrict__ emb,
                                          const unsigned char* __restrict__ tab,
                                          const int* __restrict__ trow, int lcol0,
                                          int lane, f32x4 acc[2][NI]) {
    int ln = lane & 15, quad = lane >> 4;
#pragma unroll
    for (int mi = 0; mi < 2; ++mi)
#pragma unroll
        for (int ni = 0; ni < NI; ++ni) acc[mi][ni] = (f32x4)0.0f;

    int arow0 = ln * 40;            // m = ln      (mi=0)
    int arow1 = (16 + ln) * 40;     // m = 16+ln   (mi=1)
    int key = ln & 7;
    const unsigned char* sAb = (const unsigned char*)sA;
    int lo0 = A_LO_OFF + ln * A_LO_STRIDE;
    int lo1 = A_LO_OFF + (16 + ln) * A_LO_STRIDE;
    int qo = quad * 8;

    if (FAST) {
        const unsigned char* rp[NI];
#pragma unroll
        for (int ni = 0; ni < NI; ++ni) {
            int tok = trow[lcol0 + ni * 16 + ln];
            rp[ni] = tab + (size_t)tok * TROWB;
        }
        // depth-2 pipeline: hi half8 + lo u8x8 double-buffered, base+imm loads
        half8_t bh[2][NI]; uint2 bl8[2][NI];
#pragma unroll
        for (int ni = 0; ni < NI; ++ni) {
            bh[0][ni]  = *(const half8_t*)(rp[ni] + 2 * qo);
            bl8[0][ni] = *(const uint2*)(rp[ni] + 640 + qo);
        }
#pragma unroll
        for (int ks = 0; ks < 10; ++ks) {
            int cur = ks & 1, nxt = cur ^ 1;
            if (ks < 9) {
                int ko = (ks + 1) * 32 + qo;
#pragma unroll
                for (int ni = 0; ni < NI; ++ni) {
                    bh[nxt][ni]  = *(const half8_t*)(rp[ni] + 2 * ko);
                    bl8[nxt][ni] = *(const uint2*)(rp[ni] + 640 + ko);
                }
            }
            int sp = (ks * 4 + quad) ^ key;
            int lslot = (ks * 4 + quad) * 8;
            half8_t ah[2], al[2];
            ah[0] = __builtin_bit_cast(half8_t, sA[arow0 + sp]);
            ah[1] = __builtin_bit_cast(half8_t, sA[arow1 + sp]);
            al[0] = decode_lo8(*(const uint2*)(sAb + lo0 + lslot));
            al[1] = decode_lo8(*(const uint2*)(sAb + lo1 + lslot));
            half8_t bl[NI];
#pragma unroll
            for (int ni = 0; ni < NI; ++ni) bl[ni] = decode_lo8(bl8[cur][ni]);
#pragma unroll
            for (int mi = 0; mi < 2; ++mi)
#pragma unroll
                for (int ni = 0; ni < NI; ++ni) {
                    acc[mi][ni] = __builtin_amdgcn_mfma_f32_16x16x32_f16(ah[mi], bh[cur][ni], acc[mi][ni], 0, 0, 0);
                    acc[mi][ni] = __builtin_amdgcn_mfma_f32_16x16x32_f16(ah[mi], bl[ni], acc[mi][ni], 0, 0, 0);
                    acc[mi][ni] = __builtin_amdgcn_mfma_f32_16x16x32_f16(al[mi], bh[cur][ni], acc[mi][ni], 0, 0, 0);
                }
        }
    } else {
        const float* bp[NI];
#pragma unroll
        for (int ni = 0; ni < NI; ++ni) {
            int tok = trow[lcol0 + ni * 16 + ln];
            bp[ni] = emb + (size_t)tok * D;
        }
#pragma unroll 1
        for (int ks = 0; ks < 10; ++ks) {
            int kb = ks * 32 + qo;
            int ka = kb > 296 ? 296 : kb;
            int kb4 = kb + 4;
            int kbb = kb4 > 296 ? 296 : kb4;
            float4 b0[NI], b1[NI];
#pragma unroll
            for (int ni = 0; ni < NI; ++ni) {
                b0[ni] = *(const float4*)(bp[ni] + ka);
                b1[ni] = *(const float4*)(bp[ni] + kbb);
            }
            if (kb >= 296) {
                float4 z = make_float4(0.f, 0.f, 0.f, 0.f);
#pragma unroll
                for (int ni = 0; ni < NI; ++ni) {
                    if (kb >= 300) b0[ni] = z;
                    b1[ni] = z;
                }
            }
            int sp = (ks * 4 + quad) ^ key;
            int lslot = (ks * 4 + quad) * 8;
            half8_t ah[2], al[2];
            ah[0] = __builtin_bit_cast(half8_t, sA[arow0 + sp]);
            ah[1] = __builtin_bit_cast(half8_t, sA[arow1 + sp]);
            al[0] = decode_lo8(*(const uint2*)(sAb + lo0 + lslot));
            al[1] = decode_lo8(*(const uint2*)(sAb + lo1 + lslot));
            half8_t bh[NI], bl[NI];
#pragma unroll
            for (int ni = 0; ni < NI; ++ni) split8(b0[ni], b1[ni], bh[ni], bl[ni]);
#pragma unroll
            for (int mi = 0; mi < 2; ++mi)
#pragma unroll
                for (int ni = 0; ni < NI; ++ni) {
                    acc[mi][ni] = __builtin_amdgcn_mfma_f32_16x16x32_f16(ah[mi], bh[ni], acc[mi][ni], 0, 0, 0);
                    acc[mi][ni] = __builtin_amdgcn_mfma_f32_16x16x32_f16(ah[mi], bl[ni], acc[mi][ni], 0, 0, 0);
                    acc[mi][ni] = __builtin_amdgcn_mfma_f32_16x16x32_f16(al[mi], bh[ni], acc[mi][ni], 0, 0, 0);
                }
        }
    }
}

__device__ __forceinline__ float xmax4(float v) {
    v = fmaxf(v, __shfl_xor(v, 1)); v = fmaxf(v, __shfl_xor(v, 2));
    v = fmaxf(v, __shfl_xor(v, 4)); v = fmaxf(v, __shfl_xor(v, 8));
    return v;
}
__device__ __forceinline__ float xsum4(float v) {
    v += __shfl_xor(v, 1); v += __shfl_xor(v, 2);
    v += __shfl_xor(v, 4); v += __shfl_xor(v, 8);
    return v;
}

// ---------------- K2: target scores (wave-per-t, barrier-free K-loop) --------
template<bool FAST>
__global__ __launch_bounds__(256, 5) void k_scores(const int* __restrict__ targets,
                                                   const float* __restrict__ emb,
                                                   const unsigned char* __restrict__ tab,
                                                   const unsigned char* __restrict__ wsA,
                                                   float* __restrict__ wsScr) {
    __shared__ __align__(16) uint4 sA[A_IMG_U4];   // 30976 B -> 5 blocks/CU
    int b = blockIdx.y, tid = threadIdx.x;
    {
        const uint4* src = (const uint4*)(wsA + (size_t)b * A_IMG_BYTES);
        for (int i = tid; i < A_IMG_U4; i += 256) sA[i] = src[i];
    }
    __syncthreads();

    int lane = tid & 63, wave = tid >> 6;
    int t = blockIdx.x * 4 + wave;
    const int* trow = targets + ((size_t)b * T_ + t) * LT;

    f32x4 acc[2][4];
    compute_U<FAST, 4>(sA, emb, tab, trow, 0, lane, acc);

    // softmax over l per c, max over c, sum over l — all in-wave
    float score_l[4] = {0.f, 0.f, 0.f, 0.f};
#pragma unroll
    for (int mi = 0; mi < 2; ++mi)
#pragma unroll
        for (int r = 0; r < 4; ++r) {
            float m = fmaxf(fmaxf(acc[mi][0][r], acc[mi][1][r]),
                            fmaxf(acc[mi][2][r], acc[mi][3][r]));
            m = xmax4(m);                     // max over 64 l for this c
            float p[4], s = 0.f;
#pragma unroll
            for (int ni = 0; ni < 4; ++ni) { p[ni] = __expf(acc[mi][ni][r] - m); s += p[ni]; }
            s = xsum4(s);                     // denom over 64 l
            float rv = 1.0f / s;
#pragma unroll
            for (int ni = 0; ni < 4; ++ni) score_l[ni] = fmaxf(score_l[ni], p[ni] * rv);
        }
    float tot = 0.f;
#pragma unroll
    for (int ni = 0; ni < 4; ++ni) {
        float v = score_l[ni];                // fold max over c across quads
        v = fmaxf(v, __shfl_xor(v, 16));
        v = fmaxf(v, __shfl_xor(v, 32));
        tot += v;
    }
    tot = xsum4(tot);                         // sum over the 16 ln-columns
    if (lane == 0) wsScr[b * T_ + t] = tot;
}

// ---------------- K3: top-5 per batch (descending, lowest-index ties) --------
__global__ void k_topn(const float* __restrict__ wsScr, int* __restrict__ wsIdx) {
    int b = blockIdx.x;
    int tid = threadIdx.x;              // 64 threads = 1 wave
    float v[4];
    for (int i = 0; i < 4; ++i) v[i] = wsScr[b * T_ + tid + 64 * i];
    for (int r = 0; r < NSEL; ++r) {
        float bv = v[0]; int bi = tid;
        for (int i = 1; i < 4; ++i) {
            int idx = tid + 64 * i;
            if (v[i] > bv) { bv = v[i]; bi = idx; }
        }
        for (int off = 32; off > 0; off >>= 1) {
            float ov = __shfl_down(bv, off);
            int   oi = __shfl_down(bi, off);
            if (ov > bv || (ov == bv && oi < bi)) { bv = ov; bi = oi; }
        }
        bi = __shfl(bi, 0);
        if (tid == 0) wsIdx[b * NSEL + r] = bi;
        if ((bi & 63) == tid) v[bi >> 6] = -1e30f;   // remove winner
    }
}

// ---------------- K4: recompute selected tiles, L2-normalize rows ------------
// One 256-thread block per (b, j); wave w computes l-columns [w*16, w*16+16).
template<bool FAST>
__global__ __launch_bounds__(256) void k_output(const int* __restrict__ targets,
                                                const float* __restrict__ emb,
                                                const unsigned char* __restrict__ tab,
                                                const unsigned char* __restrict__ wsA,
                                                const int* __restrict__ wsIdx,
                                                float* __restrict__ out) {
    __shared__ __align__(16) uint4 sA[A_IMG_U4];
    __shared__ float sS[LC][4];
    int b = blockIdx.y, j = blockIdx.x, tid = threadIdx.x;
    {
        const uint4* src = (const uint4*)(wsA + (size_t)b * A_IMG_BYTES);
        for (int i = tid; i < A_IMG_U4; i += 256) sA[i] = src[i];
    }
    __syncthreads();

    int lane = tid & 63, wave = tid >> 6;
    int t = wsIdx[b * NSEL + j];
    const int* trow = targets + ((size_t)b * T_ + t) * LT;
    f32x4 acc[2][1];
    compute_U<FAST, 1>(sA, emb, tab, trow, wave * 16, lane, acc);

    int ln = lane & 15, quad = lane >> 4;
    // partial sum of squares over this wave's 16 l's, per c
#pragma unroll
    for (int mi = 0; mi < 2; ++mi)
#pragma unroll
        for (int r = 0; r < 4; ++r) {
            float v = acc[mi][0][r] * acc[mi][0][r];
            v = xsum4(v);                       // sum over ln within quad-group
            if (ln == 0) sS[mi * 16 + quad * 4 + r][wave] = v;
        }
    __syncthreads();

    float* obase = out + (size_t)(b * NSEL + j) * (LC * LT);
#pragma unroll
    for (int mi = 0; mi < 2; ++mi)
#pragma unroll
        for (int r = 0; r < 4; ++r) {
            int c = mi * 16 + quad * 4 + r;
            float ss = sS[c][0] + sS[c][1] + sS[c][2] + sS[c][3];
            float rinv = 1.0f / sqrtf(ss);
            obase[c * LT + wave * 16 + ln] = acc[mi][0][r] * rinv;
        }
}

extern "C" void kernel_launch(void* const* d_in, const int* in_sizes, int n_in,
                              void* d_out, int out_size, void* d_ws, size_t ws_size,
                              hipStream_t stream) {
    const int*   claim   = (const int*)d_in[0];
    const int*   targets = (const int*)d_in[1];
    const float* emb     = (const float*)d_in[2];
    // d_in[3] is n (=5), compile-time NSEL

    const size_t tabBytes = (size_t)VOCAB * TROWB;                     // 51.2 MB
    const size_t restBytes = (size_t)B_ * A_IMG_BYTES
                           + (size_t)B_ * T_ * sizeof(float)
                           + (size_t)B_ * NSEL * sizeof(int) + 256;
    bool fast = ws_size >= tabBytes + restBytes;   // deterministic per run

    char* p = (char*)d_ws;
    unsigned char* tab = nullptr;
    if (fast) { tab = (unsigned char*)p; p += tabBytes; }
    unsigned char* wsA = (unsigned char*)p; p += (size_t)B_ * A_IMG_BYTES;
    float* wsScr = (float*)p;               p += (size_t)B_ * T_ * sizeof(float);
    int*   wsIdx = (int*)p;
    float* out   = (float*)d_out;

    if (fast)
        k_prep_table<<<dim3(VOCAB / 4), dim3(256), 0, stream>>>(emb, tab);
    k_prep_claim<<<dim3(B_ * LC), dim3(64), 0, stream>>>(claim, emb, wsA);
    if (fast) {
        k_scores<true><<<dim3(T_ / 4, B_), dim3(256), 0, stream>>>(targets, emb, tab, wsA, wsScr);
        k_topn<<<dim3(B_), dim3(64), 0, stream>>>(wsScr, wsIdx);
        k_output<true><<<dim3(NSEL, B_), dim3(256), 0, stream>>>(targets, emb, tab, wsA, wsIdx, out);
    } else {
        k_scores<false><<<dim3(T_ / 4, B_), dim3(256), 0, stream>>>(targets, emb, tab, wsA, wsScr);
        k_topn<<<dim3(B_), dim3(64), 0, stream>>>(wsScr, wsIdx);
        k_output<false><<<dim3(NSEL, B_), dim3(256), 0, stream>>>(targets, emb, tab, wsA, wsIdx, out);
    }
}

// Round 12
// 336.238 us; speedup vs baseline: 1.5136x; 1.5136x over previous
//
#include <hip/hip_runtime.h>
#include <hip/hip_bf16.h>

// Problem constants (fixed by the reference)
#define VOCAB 50000
#define D     300
#define B_    64
#define LC    32
#define T_    256
#define LT    64
#define NSEL  5

// B table row: 1024 B, 128-line aligned:
//   [f16 hi x320 = 640 B][u8 e5m2-trunc lo x320 = 320 B][64 B zero pad]
#define TROWB  1024
// A image per batch (ws + LDS), 30976 B total:
//   hi: uint4[0..1280)  = 32 rows x 40 slots (16 B), slot s at s^(m&7) (swizzled)
//   lo: bytes [20480..30976) = 32 rows x 328 B (8 B per k-slot, 8 B pad/row)
#define A_HI_U4    1280
#define A_LO_OFF   20480
#define A_LO_STRIDE 328
#define A_IMG_BYTES 30976
#define A_IMG_U4    1936

typedef _Float16 half8_t __attribute__((ext_vector_type(8)));
typedef _Float16 half4_t __attribute__((ext_vector_type(4)));
typedef float    f32x4   __attribute__((ext_vector_type(4)));

// e5m2-style lo encode: rounded high byte of f16 bits (lo tiny -> no overflow)
__device__ __forceinline__ unsigned char enc_lo(float x, _Float16 h) {
    _Float16 l = (_Float16)(x - (float)h);
    unsigned short b = __builtin_bit_cast(unsigned short, l);
    return (unsigned char)((unsigned short)(b + 0x80) >> 8);
}

// decode 8 lo-bytes -> half8 (f16 = byte << 8)
__device__ __forceinline__ half8_t decode_lo8(uint2 w) {
    unsigned int a = w.x, b = w.y;
    unsigned int p0 = ((a & 0xFFu) << 8) | ((a & 0xFF00u) << 16);
    unsigned int p1 = ((a & 0xFF0000u) >> 8) | (a & 0xFF000000u);
    unsigned int p2 = ((b & 0xFFu) << 8) | ((b & 0xFF00u) << 16);
    unsigned int p3 = ((b & 0xFF0000u) >> 8) | (b & 0xFF000000u);
    uint4 r = make_uint4(p0, p1, p2, p3);
    return __builtin_bit_cast(half8_t, r);
}

// ---------------- K0: whole-table f16hi + u8lo conversion (1024 B rows) ------
__global__ __launch_bounds__(256) void k_prep_table(const float* __restrict__ emb,
                                                    unsigned char* __restrict__ tab) {
    int r = blockIdx.x * 4 + (threadIdx.x >> 6);     // 12500*4 = 50000 rows
    int lane = threadIdx.x & 63;
    const float* src = emb + (size_t)r * D;
    unsigned char* row = tab + (size_t)r * TROWB;
#pragma unroll
    for (int i = 0; i < 2; ++i) {
        int k4 = lane + i * 64;                      // float4 index < 80
        if (k4 >= 80) continue;
        float4 v = (k4 < 75) ? *(const float4*)(src + 4 * k4)
                             : make_float4(0.f, 0.f, 0.f, 0.f);
        _Float16 h0 = (_Float16)v.x, h1 = (_Float16)v.y;
        _Float16 h2 = (_Float16)v.z, h3 = (_Float16)v.w;
        half4_t hv; hv[0] = h0; hv[1] = h1; hv[2] = h2; hv[3] = h3;
        *(half4_t*)(row + 8 * k4) = hv;
        unsigned int lw = (unsigned int)enc_lo(v.x, h0)
                        | ((unsigned int)enc_lo(v.y, h1) << 8)
                        | ((unsigned int)enc_lo(v.z, h2) << 16)
                        | ((unsigned int)enc_lo(v.w, h3) << 24);
        *(unsigned int*)(row + 640 + 4 * k4) = lw;
    }
    if (lane < 4)                                    // zero the 64 B pad
        *(uint4*)(row + 960 + 16 * lane) = make_uint4(0, 0, 0, 0);
}

// ---------------- K1: claim -> packed hi/lo swizzled image in ws -------------
__global__ void k_prep_claim(const int* __restrict__ claim,
                             const float* __restrict__ emb,
                             unsigned char* __restrict__ wsA) {
    int row = blockIdx.x;                 // 0..B_*LC-1
    int b = row >> 5, m = row & 31;
    int tok = claim[row];
    const float* src = emb + (size_t)tok * D;
    unsigned char* base = wsA + (size_t)b * A_IMG_BYTES;
    _Float16* hbase = (_Float16*)base;
    for (int k = threadIdx.x; k < 320; k += 64) {
        float x = (k < D) ? src[k] : 0.0f;
        _Float16 h = (_Float16)x;
        int sp = ((k >> 3) ^ (m & 7));
        hbase[(m * 40 + sp) * 8 + (k & 7)] = h;
        base[A_LO_OFF + m * A_LO_STRIDE + (k >> 3) * 8 + (k & 7)] = enc_lo(x, h);
    }
}

// hi/lo split of a float4 pair into half8 hi and half8 lo (slow path only)
__device__ __forceinline__ void split8(const float4& a, const float4& b,
                                       half8_t& hv, half8_t& lv) {
    float x[8] = {a.x, a.y, a.z, a.w, b.x, b.y, b.z, b.w};
#pragma unroll
    for (int i = 0; i < 8; ++i) {
        _Float16 h = (_Float16)x[i];
        hv[i] = h;
        lv[i] = (_Float16)(x[i] - (float)h);
    }
}

// ---------------- shared K-loop: U tile via f16x2-split MFMA ------------------
// acc[mi][ni] covers c = mi*16+quad*4+reg, l = lcol0 + ni*16 + ln.
// FAST path: depth-3 triple-buffered B-fragment pipeline (12 loads in flight).
template<bool FAST, int NI>
__device__ __forceinline__ void compute_U(const uint4* sA,
                                          const float* __restrict__ emb,
                                          const unsigned char* __restrict__ tab,
                                          const int* __restrict__ trow, int lcol0,
                                          int lane, f32x4 acc[2][NI]) {
    int ln = lane & 15, quad = lane >> 4;
#pragma unroll
    for (int mi = 0; mi < 2; ++mi)
#pragma unroll
        for (int ni = 0; ni < NI; ++ni) acc[mi][ni] = (f32x4)0.0f;

    int arow0 = ln * 40;            // m = ln      (mi=0)
    int arow1 = (16 + ln) * 40;     // m = 16+ln   (mi=1)
    int key = ln & 7;
    const unsigned char* sAb = (const unsigned char*)sA;
    int lo0 = A_LO_OFF + ln * A_LO_STRIDE;
    int lo1 = A_LO_OFF + (16 + ln) * A_LO_STRIDE;
    int qo = quad * 8;

    if (FAST) {
        const unsigned char* rp[NI];
#pragma unroll
        for (int ni = 0; ni < NI; ++ni) {
            int tok = trow[lcol0 + ni * 16 + ln];
            rp[ni] = tab + (size_t)tok * TROWB;
        }
        half8_t bh[3][NI]; uint2 bl8[3][NI];
#pragma unroll
        for (int s = 0; s < 2; ++s) {
            int ko = s * 32 + qo;
#pragma unroll
            for (int ni = 0; ni < NI; ++ni) {
                bh[s][ni]  = *(const half8_t*)(rp[ni] + 2 * ko);
                bl8[s][ni] = *(const uint2*)(rp[ni] + 640 + ko);
            }
        }
#pragma unroll
        for (int ks = 0; ks < 10; ++ks) {
            int cur = ks % 3;
            if (ks < 8) {
                int pre = (ks + 2) % 3;
                int ko = (ks + 2) * 32 + qo;
#pragma unroll
                for (int ni = 0; ni < NI; ++ni) {
                    bh[pre][ni]  = *(const half8_t*)(rp[ni] + 2 * ko);
                    bl8[pre][ni] = *(const uint2*)(rp[ni] + 640 + ko);
                }
            }
            int sp = (ks * 4 + quad) ^ key;
            int lslot = (ks * 4 + quad) * 8;
            half8_t ah[2], al[2];
            ah[0] = __builtin_bit_cast(half8_t, sA[arow0 + sp]);
            ah[1] = __builtin_bit_cast(half8_t, sA[arow1 + sp]);
            al[0] = decode_lo8(*(const uint2*)(sAb + lo0 + lslot));
            al[1] = decode_lo8(*(const uint2*)(sAb + lo1 + lslot));
            half8_t bl[NI];
#pragma unroll
            for (int ni = 0; ni < NI; ++ni) bl[ni] = decode_lo8(bl8[cur][ni]);
#pragma unroll
            for (int mi = 0; mi < 2; ++mi)
#pragma unroll
                for (int ni = 0; ni < NI; ++ni) {
                    acc[mi][ni] = __builtin_amdgcn_mfma_f32_16x16x32_f16(ah[mi], bh[cur][ni], acc[mi][ni], 0, 0, 0);
                    acc[mi][ni] = __builtin_amdgcn_mfma_f32_16x16x32_f16(ah[mi], bl[ni], acc[mi][ni], 0, 0, 0);
                    acc[mi][ni] = __builtin_amdgcn_mfma_f32_16x16x32_f16(al[mi], bh[cur][ni], acc[mi][ni], 0, 0, 0);
                }
        }
    } else {
        const float* bp[NI];
#pragma unroll
        for (int ni = 0; ni < NI; ++ni) {
            int tok = trow[lcol0 + ni * 16 + ln];
            bp[ni] = emb + (size_t)tok * D;
        }
#pragma unroll 1
        for (int ks = 0; ks < 10; ++ks) {
            int kb = ks * 32 + qo;
            int ka = kb > 296 ? 296 : kb;
            int kb4 = kb + 4;
            int kbb = kb4 > 296 ? 296 : kb4;
            float4 b0[NI], b1[NI];
#pragma unroll
            for (int ni = 0; ni < NI; ++ni) {
                b0[ni] = *(const float4*)(bp[ni] + ka);
                b1[ni] = *(const float4*)(bp[ni] + kbb);
            }
            if (kb >= 296) {
                float4 z = make_float4(0.f, 0.f, 0.f, 0.f);
#pragma unroll
                for (int ni = 0; ni < NI; ++ni) {
                    if (kb >= 300) b0[ni] = z;
                    b1[ni] = z;
                }
            }
            int sp = (ks * 4 + quad) ^ key;
            int lslot = (ks * 4 + quad) * 8;
            half8_t ah[2], al[2];
            ah[0] = __builtin_bit_cast(half8_t, sA[arow0 + sp]);
            ah[1] = __builtin_bit_cast(half8_t, sA[arow1 + sp]);
            al[0] = decode_lo8(*(const uint2*)(sAb + lo0 + lslot));
            al[1] = decode_lo8(*(const uint2*)(sAb + lo1 + lslot));
            half8_t bh[NI], bl[NI];
#pragma unroll
            for (int ni = 0; ni < NI; ++ni) split8(b0[ni], b1[ni], bh[ni], bl[ni]);
#pragma unroll
            for (int mi = 0; mi < 2; ++mi)
#pragma unroll
                for (int ni = 0; ni < NI; ++ni) {
                    acc[mi][ni] = __builtin_amdgcn_mfma_f32_16x16x32_f16(ah[mi], bh[ni], acc[mi][ni], 0, 0, 0);
                    acc[mi][ni] = __builtin_amdgcn_mfma_f32_16x16x32_f16(ah[mi], bl[ni], acc[mi][ni], 0, 0, 0);
                    acc[mi][ni] = __builtin_amdgcn_mfma_f32_16x16x32_f16(al[mi], bh[ni], acc[mi][ni], 0, 0, 0);
                }
        }
    }
}

__device__ __forceinline__ float xmax4(float v) {
    v = fmaxf(v, __shfl_xor(v, 1)); v = fmaxf(v, __shfl_xor(v, 2));
    v = fmaxf(v, __shfl_xor(v, 4)); v = fmaxf(v, __shfl_xor(v, 8));
    return v;
}
__device__ __forceinline__ float xsum4(float v) {
    v += __shfl_xor(v, 1); v += __shfl_xor(v, 2);
    v += __shfl_xor(v, 4); v += __shfl_xor(v, 8);
    return v;
}

// ---------------- K2: target scores (wave-per-t, barrier-free K-loop) --------
template<bool FAST>
__global__ __launch_bounds__(256, 4) void k_scores(const int* __restrict__ targets,
                                                   const float* __restrict__ emb,
                                                   const unsigned char* __restrict__ tab,
                                                   const unsigned char* __restrict__ wsA,
                                                   float* __restrict__ wsScr) {
    __shared__ __align__(16) uint4 sA[A_IMG_U4];   // 30976 B
    int b = blockIdx.y, tid = threadIdx.x;
    {
        const uint4* src = (const uint4*)(wsA + (size_t)b * A_IMG_BYTES);
        for (int i = tid; i < A_IMG_U4; i += 256) sA[i] = src[i];
    }
    __syncthreads();

    int lane = tid & 63, wave = tid >> 6;
    int t = blockIdx.x * 4 + wave;
    const int* trow = targets + ((size_t)b * T_ + t) * LT;

    f32x4 acc[2][4];
    compute_U<FAST, 4>(sA, emb, tab, trow, 0, lane, acc);

    // softmax over l per c, max over c, sum over l — all in-wave
    float score_l[4] = {0.f, 0.f, 0.f, 0.f};
#pragma unroll
    for (int mi = 0; mi < 2; ++mi)
#pragma unroll
        for (int r = 0; r < 4; ++r) {
            float m = fmaxf(fmaxf(acc[mi][0][r], acc[mi][1][r]),
                            fmaxf(acc[mi][2][r], acc[mi][3][r]));
            m = xmax4(m);                     // max over 64 l for this c
            float p[4], s = 0.f;
#pragma unroll
            for (int ni = 0; ni < 4; ++ni) { p[ni] = __expf(acc[mi][ni][r] - m); s += p[ni]; }
            s = xsum4(s);                     // denom over 64 l
            float rv = 1.0f / s;
#pragma unroll
            for (int ni = 0; ni < 4; ++ni) score_l[ni] = fmaxf(score_l[ni], p[ni] * rv);
        }
    float tot = 0.f;
#pragma unroll
    for (int ni = 0; ni < 4; ++ni) {
        float v = score_l[ni];                // fold max over c across quads
        v = fmaxf(v, __shfl_xor(v, 16));
        v = fmaxf(v, __shfl_xor(v, 32));
        tot += v;
    }
    tot = xsum4(tot);                         // sum over the 16 ln-columns
    if (lane == 0) wsScr[b * T_ + t] = tot;
}

// ---------------- K3: top-5 per batch (descending, lowest-index ties) --------
__global__ void k_topn(const float* __restrict__ wsScr, int* __restrict__ wsIdx) {
    int b = blockIdx.x;
    int tid = threadIdx.x;              // 64 threads = 1 wave
    float v[4];
    for (int i = 0; i < 4; ++i) v[i] = wsScr[b * T_ + tid + 64 * i];
    for (int r = 0; r < NSEL; ++r) {
        float bv = v[0]; int bi = tid;
        for (int i = 1; i < 4; ++i) {
            int idx = tid + 64 * i;
            if (v[i] > bv) { bv = v[i]; bi = idx; }
        }
        for (int off = 32; off > 0; off >>= 1) {
            float ov = __shfl_down(bv, off);
            int   oi = __shfl_down(bi, off);
            if (ov > bv || (ov == bv && oi < bi)) { bv = ov; bi = oi; }
        }
        bi = __shfl(bi, 0);
        if (tid == 0) wsIdx[b * NSEL + r] = bi;
        if ((bi & 63) == tid) v[bi >> 6] = -1e30f;   // remove winner
    }
}

// ---------------- K4: recompute selected tiles, L2-normalize rows ------------
// One 256-thread block per (b, j); wave w computes l-columns [w*16, w*16+16).
template<bool FAST>
__global__ __launch_bounds__(256) void k_output(const int* __restrict__ targets,
                                                const float* __restrict__ emb,
                                                const unsigned char* __restrict__ tab,
                                                const unsigned char* __restrict__ wsA,
                                                const int* __restrict__ wsIdx,
                                                float* __restrict__ out) {
    __shared__ __align__(16) uint4 sA[A_IMG_U4];
    __shared__ float sS[LC][4];
    int b = blockIdx.y, j = blockIdx.x, tid = threadIdx.x;
    {
        const uint4* src = (const uint4*)(wsA + (size_t)b * A_IMG_BYTES);
        for (int i = tid; i < A_IMG_U4; i += 256) sA[i] = src[i];
    }
    __syncthreads();

    int lane = tid & 63, wave = tid >> 6;
    int t = wsIdx[b * NSEL + j];
    const int* trow = targets + ((size_t)b * T_ + t) * LT;
    f32x4 acc[2][1];
    compute_U<FAST, 1>(sA, emb, tab, trow, wave * 16, lane, acc);

    int ln = lane & 15, quad = lane >> 4;
    // partial sum of squares over this wave's 16 l's, per c
#pragma unroll
    for (int mi = 0; mi < 2; ++mi)
#pragma unroll
        for (int r = 0; r < 4; ++r) {
            float v = acc[mi][0][r] * acc[mi][0][r];
            v = xsum4(v);                       // sum over ln within quad-group
            if (ln == 0) sS[mi * 16 + quad * 4 + r][wave] = v;
        }
    __syncthreads();

    float* obase = out + (size_t)(b * NSEL + j) * (LC * LT);
#pragma unroll
    for (int mi = 0; mi < 2; ++mi)
#pragma unroll
        for (int r = 0; r < 4; ++r) {
            int c = mi * 16 + quad * 4 + r;
            float ss = sS[c][0] + sS[c][1] + sS[c][2] + sS[c][3];
            float rinv = 1.0f / sqrtf(ss);
            obase[c * LT + wave * 16 + ln] = acc[mi][0][r] * rinv;
        }
}

extern "C" void kernel_launch(void* const* d_in, const int* in_sizes, int n_in,
                              void* d_out, int out_size, void* d_ws, size_t ws_size,
                              hipStream_t stream) {
    const int*   claim   = (const int*)d_in[0];
    const int*   targets = (const int*)d_in[1];
    const float* emb     = (const float*)d_in[2];
    // d_in[3] is n (=5), compile-time NSEL

    const size_t tabBytes = (size_t)VOCAB * TROWB;                     // 51.2 MB
    const size_t restBytes = (size_t)B_ * A_IMG_BYTES
                           + (size_t)B_ * T_ * sizeof(float)
                           + (size_t)B_ * NSEL * sizeof(int) + 256;
    bool fast = ws_size >= tabBytes + restBytes;   // deterministic per run

    char* p = (char*)d_ws;
    unsigned char* tab = nullptr;
    if (fast) { tab = (unsigned char*)p; p += tabBytes; }
    unsigned char* wsA = (unsigned char*)p; p += (size_t)B_ * A_IMG_BYTES;
    float* wsScr = (float*)p;               p += (size_t)B_ * T_ * sizeof(float);
    int*   wsIdx = (int*)p;
    float* out   = (float*)d_out;

    if (fast)
        k_prep_table<<<dim3(VOCAB / 4), dim3(256), 0, stream>>>(emb, tab);
    k_prep_claim<<<dim3(B_ * LC), dim3(64), 0, stream>>>(claim, emb, wsA);
    if (fast) {
        k_scores<true><<<dim3(T_ / 4, B_), dim3(256), 0, stream>>>(targets, emb, tab, wsA, wsScr);
        k_topn<<<dim3(B_), dim3(64), 0, stream>>>(wsScr, wsIdx);
        k_output<true><<<dim3(NSEL, B_), dim3(256), 0, stream>>>(targets, emb, tab, wsA, wsIdx, out);
    } else {
        k_scores<false><<<dim3(T_ / 4, B_), dim3(256), 0, stream>>>(targets, emb, tab, wsA, wsScr);
        k_topn<<<dim3(B_), dim3(64), 0, stream>>>(wsScr, wsIdx);
        k_output<false><<<dim3(NSEL, B_), dim3(256), 0, stream>>>(targets, emb, tab, wsA, wsIdx, out);
    }
}

// Round 13
// 301.310 us; speedup vs baseline: 1.6890x; 1.1159x over previous
//
#include <hip/hip_runtime.h>
#include <hip/hip_bf16.h>

// Problem constants (fixed by the reference)
#define VOCAB 50000
#define D     300
#define B_    64
#define LC    32
#define T_    256
#define LT    64
#define NSEL  5

// A-image geometry: 32 rows x 40 slots (16B = 8 f16), k padded 300->320,
// slot s stored at s ^ (m&7) -> conflict-free ds_read_b128.
// hi: uint4[0..1280), lo: uint4[1280..2560). 40960 B per batch.
#define A_U4   2560
#define A_HALF 20480
#define TROW   640            // interleaved row: hi [0,320) | lo [320,640) halfs (1280 B, 10 lines)

typedef _Float16 half8_t __attribute__((ext_vector_type(8)));
typedef float    f32x4   __attribute__((ext_vector_type(4)));

// ---------------- K0: merged prep: table (hi|lo f16) + claim images ----------
// blocks [0, tableBlocks): 4 table rows each; blocks [tableBlocks, +512): 4 claim rows.
__global__ __launch_bounds__(256) void k_prep(const int* __restrict__ claim,
                                              const float* __restrict__ emb,
                                              _Float16* __restrict__ tab,
                                              _Float16* __restrict__ wsA,
                                              int tableBlocks) {
    int wave = threadIdx.x >> 6, lane = threadIdx.x & 63;
    if ((int)blockIdx.x < tableBlocks) {
        int r = blockIdx.x * 4 + wave;               // 12500*4 = 50000 rows
        const float* src = emb + (size_t)r * D;
        _Float16* d = tab + (size_t)r * TROW;
#pragma unroll
        for (int i = 0; i < 5; ++i) {
            int k = lane + i * 64;
            float x = (k < D) ? src[k] : 0.0f;
            _Float16 h = (_Float16)x;
            d[k] = h;
            d[320 + k] = (_Float16)(x - (float)h);
        }
    } else {
        int row = (blockIdx.x - tableBlocks) * 4 + wave;   // 0..2047
        int b = row >> 5, m = row & 31;
        int tok = claim[row];
        const float* src = emb + (size_t)tok * D;
        _Float16* base = wsA + (size_t)b * A_HALF;
#pragma unroll
        for (int i = 0; i < 5; ++i) {
            int k = lane + i * 64;
            float x = (k < D) ? src[k] : 0.0f;
            _Float16 h = (_Float16)x;
            int sp = ((k >> 3) ^ (m & 7));
            int idx = (m * 40 + sp) * 8 + (k & 7);
            base[idx] = h;
            base[10240 + idx] = (_Float16)(x - (float)h);
        }
    }
}

// hi/lo split of a float4 pair into half8 hi and half8 lo (slow path only)
__device__ __forceinline__ void split8(const float4& a, const float4& b,
                                       half8_t& hv, half8_t& lv) {
    float x[8] = {a.x, a.y, a.z, a.w, b.x, b.y, b.z, b.w};
#pragma unroll
    for (int i = 0; i < 8; ++i) {
        _Float16 h = (_Float16)x[i];
        hv[i] = h;
        lv[i] = (_Float16)(x[i] - (float)h);
    }
}

// ---------------- shared K-loop: U tile via f16x2-split MFMA ------------------
// acc[mi][ni] covers c = mi*16+quad*4+reg, l = lcol0 + ni*16 + ln.
// FAST: depth-2 double-buffered B loads from f16 hi|lo interleaved table (R8 config).
template<bool FAST, int NI>
__device__ __forceinline__ void compute_U(const uint4* sA,
                                          const float* __restrict__ emb,
                                          const _Float16* __restrict__ tab,
                                          const int* __restrict__ trow, int lcol0,
                                          int lane, f32x4 acc[2][NI]) {
    int ln = lane & 15, quad = lane >> 4;
#pragma unroll
    for (int mi = 0; mi < 2; ++mi)
#pragma unroll
        for (int ni = 0; ni < NI; ++ni) acc[mi][ni] = (f32x4)0.0f;

    int arow0 = ln * 40;            // m = ln      (mi=0)
    int arow1 = (16 + ln) * 40;     // m = 16+ln   (mi=1)
    int key = ln & 7;
    int qo = quad * 8;

    if (FAST) {
        const _Float16* rp[NI];
#pragma unroll
        for (int ni = 0; ni < NI; ++ni) {
            int tok = trow[lcol0 + ni * 16 + ln];
            rp[ni] = tab + (size_t)tok * TROW;
        }
        // depth-2 pipeline: hi half8 + lo half8 double-buffered, base+imm loads
        half8_t bh[2][NI], bl[2][NI];
#pragma unroll
        for (int ni = 0; ni < NI; ++ni) {
            bh[0][ni] = *(const half8_t*)(rp[ni] + qo);
            bl[0][ni] = *(const half8_t*)(rp[ni] + 320 + qo);
        }
#pragma unroll
        for (int ks = 0; ks < 10; ++ks) {
            int cur = ks & 1, nxt = cur ^ 1;
            if (ks < 9) {
                int ko = (ks + 1) * 32 + qo;
#pragma unroll
                for (int ni = 0; ni < NI; ++ni) {
                    bh[nxt][ni] = *(const half8_t*)(rp[ni] + ko);
                    bl[nxt][ni] = *(const half8_t*)(rp[ni] + 320 + ko);
                }
            }
            int sp = (ks * 4 + quad) ^ key;
            half8_t ah[2], al[2];
            ah[0] = __builtin_bit_cast(half8_t, sA[arow0 + sp]);
            al[0] = __builtin_bit_cast(half8_t, sA[1280 + arow0 + sp]);
            ah[1] = __builtin_bit_cast(half8_t, sA[arow1 + sp]);
            al[1] = __builtin_bit_cast(half8_t, sA[1280 + arow1 + sp]);
#pragma unroll
            for (int mi = 0; mi < 2; ++mi)
#pragma unroll
                for (int ni = 0; ni < NI; ++ni) {
                    acc[mi][ni] = __builtin_amdgcn_mfma_f32_16x16x32_f16(ah[mi], bh[cur][ni], acc[mi][ni], 0, 0, 0);
                    acc[mi][ni] = __builtin_amdgcn_mfma_f32_16x16x32_f16(ah[mi], bl[cur][ni], acc[mi][ni], 0, 0, 0);
                    acc[mi][ni] = __builtin_amdgcn_mfma_f32_16x16x32_f16(al[mi], bh[cur][ni], acc[mi][ni], 0, 0, 0);
                }
        }
    } else {
        const float* bp[NI];
#pragma unroll
        for (int ni = 0; ni < NI; ++ni) {
            int tok = trow[lcol0 + ni * 16 + ln];
            bp[ni] = emb + (size_t)tok * D;
        }
#pragma unroll 1
        for (int ks = 0; ks < 10; ++ks) {
            int kb = ks * 32 + qo;
            int ka = kb > 296 ? 296 : kb;
            int kb4 = kb + 4;
            int kbb = kb4 > 296 ? 296 : kb4;
            float4 b0[NI], b1[NI];
#pragma unroll
            for (int ni = 0; ni < NI; ++ni) {
                b0[ni] = *(const float4*)(bp[ni] + ka);
                b1[ni] = *(const float4*)(bp[ni] + kbb);
            }
            if (kb >= 296) {
                float4 z = make_float4(0.f, 0.f, 0.f, 0.f);
#pragma unroll
                for (int ni = 0; ni < NI; ++ni) {
                    if (kb >= 300) b0[ni] = z;
                    b1[ni] = z;
                }
            }
            int sp = (ks * 4 + quad) ^ key;
            half8_t ah[2], al[2];
            ah[0] = __builtin_bit_cast(half8_t, sA[arow0 + sp]);
            al[0] = __builtin_bit_cast(half8_t, sA[1280 + arow0 + sp]);
            ah[1] = __builtin_bit_cast(half8_t, sA[arow1 + sp]);
            al[1] = __builtin_bit_cast(half8_t, sA[1280 + arow1 + sp]);
            half8_t bh[NI], bl[NI];
#pragma unroll
            for (int ni = 0; ni < NI; ++ni) split8(b0[ni], b1[ni], bh[ni], bl[ni]);
#pragma unroll
            for (int mi = 0; mi < 2; ++mi)
#pragma unroll
                for (int ni = 0; ni < NI; ++ni) {
                    acc[mi][ni] = __builtin_amdgcn_mfma_f32_16x16x32_f16(ah[mi], bh[ni], acc[mi][ni], 0, 0, 0);
                    acc[mi][ni] = __builtin_amdgcn_mfma_f32_16x16x32_f16(ah[mi], bl[ni], acc[mi][ni], 0, 0, 0);
                    acc[mi][ni] = __builtin_amdgcn_mfma_f32_16x16x32_f16(al[mi], bh[ni], acc[mi][ni], 0, 0, 0);
                }
        }
    }
}

__device__ __forceinline__ float xmax4(float v) {
    v = fmaxf(v, __shfl_xor(v, 1)); v = fmaxf(v, __shfl_xor(v, 2));
    v = fmaxf(v, __shfl_xor(v, 4)); v = fmaxf(v, __shfl_xor(v, 8));
    return v;
}
__device__ __forceinline__ float xsum4(float v) {
    v += __shfl_xor(v, 1); v += __shfl_xor(v, 2);
    v += __shfl_xor(v, 4); v += __shfl_xor(v, 8);
    return v;
}

// ---------------- K2: target scores (wave-per-t, barrier-free K-loop) --------
template<bool FAST>
__global__ __launch_bounds__(256, 4) void k_scores(const int* __restrict__ targets,
                                                   const float* __restrict__ emb,
                                                   const _Float16* __restrict__ tab,
                                                   const _Float16* __restrict__ wsA,
                                                   float* __restrict__ wsScr) {
    __shared__ __align__(16) uint4 sA[A_U4];   // 40960 B -> 4 blocks/CU
    int b = blockIdx.y, tid = threadIdx.x;
    {
        const uint4* src = (const uint4*)(wsA + (size_t)b * A_HALF);
        for (int i = tid; i < A_U4; i += 256) sA[i] = src[i];
    }
    __syncthreads();

    int lane = tid & 63, wave = tid >> 6;
    int t = blockIdx.x * 4 + wave;
    const int* trow = targets + ((size_t)b * T_ + t) * LT;

    f32x4 acc[2][4];
    compute_U<FAST, 4>(sA, emb, tab, trow, 0, lane, acc);

    // softmax over l per c, max over c, sum over l — all in-wave
    float score_l[4] = {0.f, 0.f, 0.f, 0.f};
#pragma unroll
    for (int mi = 0; mi < 2; ++mi)
#pragma unroll
        for (int r = 0; r < 4; ++r) {
            float m = fmaxf(fmaxf(acc[mi][0][r], acc[mi][1][r]),
                            fmaxf(acc[mi][2][r], acc[mi][3][r]));
            m = xmax4(m);                     // max over 64 l for this c
            float p[4], s = 0.f;
#pragma unroll
            for (int ni = 0; ni < 4; ++ni) { p[ni] = __expf(acc[mi][ni][r] - m); s += p[ni]; }
            s = xsum4(s);                     // denom over 64 l
            float rv = 1.0f / s;
#pragma unroll
            for (int ni = 0; ni < 4; ++ni) score_l[ni] = fmaxf(score_l[ni], p[ni] * rv);
        }
    float tot = 0.f;
#pragma unroll
    for (int ni = 0; ni < 4; ++ni) {
        float v = score_l[ni];                // fold max over c across quads
        v = fmaxf(v, __shfl_xor(v, 16));
        v = fmaxf(v, __shfl_xor(v, 32));
        tot += v;
    }
    tot = xsum4(tot);                         // sum over the 16 ln-columns
    if (lane == 0) wsScr[b * T_ + t] = tot;
}

// ---------------- K3: top-5 per batch (descending, lowest-index ties) --------
__global__ void k_topn(const float* __restrict__ wsScr, int* __restrict__ wsIdx) {
    int b = blockIdx.x;
    int tid = threadIdx.x;              // 64 threads = 1 wave
    float v[4];
    for (int i = 0; i < 4; ++i) v[i] = wsScr[b * T_ + tid + 64 * i];
    for (int r = 0; r < NSEL; ++r) {
        float bv = v[0]; int bi = tid;
        for (int i = 1; i < 4; ++i) {
            int idx = tid + 64 * i;
            if (v[i] > bv) { bv = v[i]; bi = idx; }
        }
        for (int off = 32; off > 0; off >>= 1) {
            float ov = __shfl_down(bv, off);
            int   oi = __shfl_down(bi, off);
            if (ov > bv || (ov == bv && oi < bi)) { bv = ov; bi = oi; }
        }
        bi = __shfl(bi, 0);
        if (tid == 0) wsIdx[b * NSEL + r] = bi;
        if ((bi & 63) == tid) v[bi >> 6] = -1e30f;   // remove winner
    }
}

// ---------------- K4: recompute selected tiles, L2-normalize rows ------------
// One 256-thread block per (b, j); wave w computes l-columns [w*16, w*16+16).
template<bool FAST>
__global__ __launch_bounds__(256) void k_output(const int* __restrict__ targets,
                                                const float* __restrict__ emb,
                                                const _Float16* __restrict__ tab,
                                                const _Float16* __restrict__ wsA,
                                                const int* __restrict__ wsIdx,
                                                float* __restrict__ out) {
    __shared__ __align__(16) uint4 sA[A_U4];
    __shared__ float sS[LC][4];
    int b = blockIdx.y, j = blockIdx.x, tid = threadIdx.x;
    {
        const uint4* src = (const uint4*)(wsA + (size_t)b * A_HALF);
        for (int i = tid; i < A_U4; i += 256) sA[i] = src[i];
    }
    __syncthreads();

    int lane = tid & 63, wave = tid >> 6;
    int t = wsIdx[b * NSEL + j];
    const int* trow = targets + ((size_t)b * T_ + t) * LT;
    f32x4 acc[2][1];
    compute_U<FAST, 1>(sA, emb, tab, trow, wave * 16, lane, acc);

    int ln = lane & 15, quad = lane >> 4;
    // partial sum of squares over this wave's 16 l's, per c
#pragma unroll
    for (int mi = 0; mi < 2; ++mi)
#pragma unroll
        for (int r = 0; r < 4; ++r) {
            float v = acc[mi][0][r] * acc[mi][0][r];
            v = xsum4(v);                       // sum over the 16 ln-columns
            if (ln == 0) sS[mi * 16 + quad * 4 + r][wave] = v;
        }
    __syncthreads();

    float* obase = out + (size_t)(b * NSEL + j) * (LC * LT);
#pragma unroll
    for (int mi = 0; mi < 2; ++mi)
#pragma unroll
        for (int r = 0; r < 4; ++r) {
            int c = mi * 16 + quad * 4 + r;
            float ss = sS[c][0] + sS[c][1] + sS[c][2] + sS[c][3];
            float rinv = 1.0f / sqrtf(ss);
            obase[c * LT + wave * 16 + ln] = acc[mi][0][r] * rinv;
        }
}

extern "C" void kernel_launch(void* const* d_in, const int* in_sizes, int n_in,
                              void* d_out, int out_size, void* d_ws, size_t ws_size,
                              hipStream_t stream) {
    const int*   claim   = (const int*)d_in[0];
    const int*   targets = (const int*)d_in[1];
    const float* emb     = (const float*)d_in[2];
    // d_in[3] is n (=5), compile-time NSEL

    const size_t tabBytes = (size_t)VOCAB * TROW * sizeof(_Float16);   // 64 MB
    const size_t restBytes = (size_t)B_ * A_HALF * sizeof(_Float16)
                           + (size_t)B_ * T_ * sizeof(float)
                           + (size_t)B_ * NSEL * sizeof(int) + 256;
    bool fast = ws_size >= tabBytes + restBytes;   // deterministic per run

    char* p = (char*)d_ws;
    _Float16* tab = nullptr;
    if (fast) { tab = (_Float16*)p; p += tabBytes; }
    _Float16* wsA = (_Float16*)p; p += (size_t)B_ * A_HALF * sizeof(_Float16);
    float* wsScr = (float*)p;     p += (size_t)B_ * T_ * sizeof(float);
    int*   wsIdx = (int*)p;
    float* out   = (float*)d_out;

    int tableBlocks = fast ? (VOCAB / 4) : 0;
    k_prep<<<dim3(tableBlocks + 512), dim3(256), 0, stream>>>(claim, emb, tab, wsA, tableBlocks);
    if (fast) {
        k_scores<true><<<dim3(T_ / 4, B_), dim3(256), 0, stream>>>(targets, emb, tab, wsA, wsScr);
        k_topn<<<dim3(B_), dim3(64), 0, stream>>>(wsScr, wsIdx);
        k_output<true><<<dim3(NSEL, B_), dim3(256), 0, stream>>>(targets, emb, tab, wsA, wsIdx, out);
    } else {
        k_scores<false><<<dim3(T_ / 4, B_), dim3(256), 0, stream>>>(targets, emb, tab, wsA, wsScr);
        k_topn<<<dim3(B_), dim3(64), 0, stream>>>(wsScr, wsIdx);
        k_output<false><<<dim3(NSEL, B_), dim3(256), 0, stream>>>(targets, emb, tab, wsA, wsIdx, out);
    }
}

// Round 14
// 299.302 us; speedup vs baseline: 1.7004x; 1.0067x over previous
//
#include <hip/hip_runtime.h>
#include <hip/hip_bf16.h>

// Problem constants (fixed by the reference)
#define VOCAB 50000
#define D     300
#define B_    64
#define LC    32
#define T_    256
#define LT    64
#define NSEL  5

// A-image geometry: 32 rows x 40 slots (16B = 8 f16), k padded 300->320,
// slot s stored at s ^ (m&7) -> conflict-free ds_read_b128.
// hi: uint4[0..1280), lo: uint4[1280..2560). 40960 B per batch.
#define A_U4   2560
#define A_HALF 20480
#define TROW   640            // interleaved row: hi [0,320) | lo [320,640) halfs (1280 B)

typedef _Float16 half8_t __attribute__((ext_vector_type(8)));
typedef float    f32x4   __attribute__((ext_vector_type(4)));

// ---------------- K0: merged prep: table (hi|lo f16) + claim images ----------
__global__ __launch_bounds__(256) void k_prep(const int* __restrict__ claim,
                                              const float* __restrict__ emb,
                                              _Float16* __restrict__ tab,
                                              _Float16* __restrict__ wsA,
                                              int tableBlocks) {
    int wave = threadIdx.x >> 6, lane = threadIdx.x & 63;
    if ((int)blockIdx.x < tableBlocks) {
        int r = blockIdx.x * 4 + wave;               // 12500*4 = 50000 rows
        const float* src = emb + (size_t)r * D;
        _Float16* d = tab + (size_t)r * TROW;
#pragma unroll
        for (int i = 0; i < 5; ++i) {
            int k = lane + i * 64;
            float x = (k < D) ? src[k] : 0.0f;
            _Float16 h = (_Float16)x;
            d[k] = h;
            d[320 + k] = (_Float16)(x - (float)h);
        }
    } else {
        int row = (blockIdx.x - tableBlocks) * 4 + wave;   // 0..2047
        int b = row >> 5, m = row & 31;
        int tok = claim[row];
        const float* src = emb + (size_t)tok * D;
        _Float16* base = wsA + (size_t)b * A_HALF;
#pragma unroll
        for (int i = 0; i < 5; ++i) {
            int k = lane + i * 64;
            float x = (k < D) ? src[k] : 0.0f;
            _Float16 h = (_Float16)x;
            int sp = ((k >> 3) ^ (m & 7));
            int idx = (m * 40 + sp) * 8 + (k & 7);
            base[idx] = h;
            base[10240 + idx] = (_Float16)(x - (float)h);
        }
    }
}

// hi/lo split of a float4 pair into half8 hi and half8 lo (slow path only)
__device__ __forceinline__ void split8(const float4& a, const float4& b,
                                       half8_t& hv, half8_t& lv) {
    float x[8] = {a.x, a.y, a.z, a.w, b.x, b.y, b.z, b.w};
#pragma unroll
    for (int i = 0; i < 8; ++i) {
        _Float16 h = (_Float16)x[i];
        hv[i] = h;
        lv[i] = (_Float16)(x[i] - (float)h);
    }
}

// ---------------- shared K-loop: U tile via f16x2-split MFMA ------------------
// acc[mi][ni] covers c = mi*16+quad*4+reg, l = lcol0 + ni*16 + ln.
// FAST: depth-2 double-buffered B loads from f16 hi|lo interleaved table.
template<bool FAST, int NI>
__device__ __forceinline__ void compute_U(const uint4* sA,
                                          const float* __restrict__ emb,
                                          const _Float16* __restrict__ tab,
                                          const int* __restrict__ trow, int lcol0,
                                          int lane, f32x4 acc[2][NI]) {
    int ln = lane & 15, quad = lane >> 4;
#pragma unroll
    for (int mi = 0; mi < 2; ++mi)
#pragma unroll
        for (int ni = 0; ni < NI; ++ni) acc[mi][ni] = (f32x4)0.0f;

    int arow0 = ln * 40;            // m = ln      (mi=0)
    int arow1 = (16 + ln) * 40;     // m = 16+ln   (mi=1)
    int key = ln & 7;
    int qo = quad * 8;

    if (FAST) {
        const _Float16* rp[NI];
#pragma unroll
        for (int ni = 0; ni < NI; ++ni) {
            int tok = trow[lcol0 + ni * 16 + ln];
            rp[ni] = tab + (size_t)tok * TROW;
        }
        // depth-2 pipeline: hi half8 + lo half8 double-buffered, base+imm loads
        half8_t bh[2][NI], bl[2][NI];
#pragma unroll
        for (int ni = 0; ni < NI; ++ni) {
            bh[0][ni] = *(const half8_t*)(rp[ni] + qo);
            bl[0][ni] = *(const half8_t*)(rp[ni] + 320 + qo);
        }
#pragma unroll
        for (int ks = 0; ks < 10; ++ks) {
            int cur = ks & 1, nxt = cur ^ 1;
            if (ks < 9) {
                int ko = (ks + 1) * 32 + qo;
#pragma unroll
                for (int ni = 0; ni < NI; ++ni) {
                    bh[nxt][ni] = *(const half8_t*)(rp[ni] + ko);
                    bl[nxt][ni] = *(const half8_t*)(rp[ni] + 320 + ko);
                }
            }
            int sp = (ks * 4 + quad) ^ key;
            half8_t ah[2], al[2];
            ah[0] = __builtin_bit_cast(half8_t, sA[arow0 + sp]);
            al[0] = __builtin_bit_cast(half8_t, sA[1280 + arow0 + sp]);
            ah[1] = __builtin_bit_cast(half8_t, sA[arow1 + sp]);
            al[1] = __builtin_bit_cast(half8_t, sA[1280 + arow1 + sp]);
#pragma unroll
            for (int mi = 0; mi < 2; ++mi)
#pragma unroll
                for (int ni = 0; ni < NI; ++ni) {
                    acc[mi][ni] = __builtin_amdgcn_mfma_f32_16x16x32_f16(ah[mi], bh[cur][ni], acc[mi][ni], 0, 0, 0);
                    acc[mi][ni] = __builtin_amdgcn_mfma_f32_16x16x32_f16(ah[mi], bl[cur][ni], acc[mi][ni], 0, 0, 0);
                    acc[mi][ni] = __builtin_amdgcn_mfma_f32_16x16x32_f16(al[mi], bh[cur][ni], acc[mi][ni], 0, 0, 0);
                }
        }
    } else {
        const float* bp[NI];
#pragma unroll
        for (int ni = 0; ni < NI; ++ni) {
            int tok = trow[lcol0 + ni * 16 + ln];
            bp[ni] = emb + (size_t)tok * D;
        }
#pragma unroll 1
        for (int ks = 0; ks < 10; ++ks) {
            int kb = ks * 32 + qo;
            int ka = kb > 296 ? 296 : kb;
            int kb4 = kb + 4;
            int kbb = kb4 > 296 ? 296 : kb4;
            float4 b0[NI], b1[NI];
#pragma unroll
            for (int ni = 0; ni < NI; ++ni) {
                b0[ni] = *(const float4*)(bp[ni] + ka);
                b1[ni] = *(const float4*)(bp[ni] + kbb);
            }
            if (kb >= 296) {
                float4 z = make_float4(0.f, 0.f, 0.f, 0.f);
#pragma unroll
                for (int ni = 0; ni < NI; ++ni) {
                    if (kb >= 300) b0[ni] = z;
                    b1[ni] = z;
                }
            }
            int sp = (ks * 4 + quad) ^ key;
            half8_t ah[2], al[2];
            ah[0] = __builtin_bit_cast(half8_t, sA[arow0 + sp]);
            al[0] = __builtin_bit_cast(half8_t, sA[1280 + arow0 + sp]);
            ah[1] = __builtin_bit_cast(half8_t, sA[arow1 + sp]);
            al[1] = __builtin_bit_cast(half8_t, sA[1280 + arow1 + sp]);
            half8_t bh[NI], bl[NI];
#pragma unroll
            for (int ni = 0; ni < NI; ++ni) split8(b0[ni], b1[ni], bh[ni], bl[ni]);
#pragma unroll
            for (int mi = 0; mi < 2; ++mi)
#pragma unroll
                for (int ni = 0; ni < NI; ++ni) {
                    acc[mi][ni] = __builtin_amdgcn_mfma_f32_16x16x32_f16(ah[mi], bh[ni], acc[mi][ni], 0, 0, 0);
                    acc[mi][ni] = __builtin_amdgcn_mfma_f32_16x16x32_f16(ah[mi], bl[ni], acc[mi][ni], 0, 0, 0);
                    acc[mi][ni] = __builtin_amdgcn_mfma_f32_16x16x32_f16(al[mi], bh[ni], acc[mi][ni], 0, 0, 0);
                }
        }
    }
}

__device__ __forceinline__ float xmax4(float v) {
    v = fmaxf(v, __shfl_xor(v, 1)); v = fmaxf(v, __shfl_xor(v, 2));
    v = fmaxf(v, __shfl_xor(v, 4)); v = fmaxf(v, __shfl_xor(v, 8));
    return v;
}
__device__ __forceinline__ float xsum4(float v) {
    v += __shfl_xor(v, 1); v += __shfl_xor(v, 2);
    v += __shfl_xor(v, 4); v += __shfl_xor(v, 8);
    return v;
}

// ---------------- K2: target scores (wave-per-t; XCD-affinity swizzle) -------
// 1-D grid of 4096. xcd = wgid&7 (CP round-robin), b = xcd*8 + (wgid>>3)/64,
// tg = (wgid>>3)&63 -> each XCD serves 8 whole b's, tg-major (L2 locality).
template<bool FAST>
__global__ __launch_bounds__(256, 4) void k_scores(const int* __restrict__ targets,
                                                   const float* __restrict__ emb,
                                                   const _Float16* __restrict__ tab,
                                                   const _Float16* __restrict__ wsA,
                                                   float* __restrict__ wsScr) {
    __shared__ __align__(16) uint4 sA[A_U4];   // 40960 B -> 4 blocks/CU
    int wg = blockIdx.x;
    int xcd = wg & 7, rest = wg >> 3;
    int b = xcd * 8 + (rest >> 6);
    int tg = rest & 63;
    int tid = threadIdx.x;
    {
        const uint4* src = (const uint4*)(wsA + (size_t)b * A_HALF);
        for (int i = tid; i < A_U4; i += 256) sA[i] = src[i];
    }
    __syncthreads();

    int lane = tid & 63, wave = tid >> 6;
    int t = tg * 4 + wave;
    const int* trow = targets + ((size_t)b * T_ + t) * LT;

    f32x4 acc[2][4];
    compute_U<FAST, 4>(sA, emb, tab, trow, 0, lane, acc);

    // softmax over l per c, max over c, sum over l — all in-wave
    float score_l[4] = {0.f, 0.f, 0.f, 0.f};
#pragma unroll
    for (int mi = 0; mi < 2; ++mi)
#pragma unroll
        for (int r = 0; r < 4; ++r) {
            float m = fmaxf(fmaxf(acc[mi][0][r], acc[mi][1][r]),
                            fmaxf(acc[mi][2][r], acc[mi][3][r]));
            m = xmax4(m);                     // max over 64 l for this c
            float p[4], s = 0.f;
#pragma unroll
            for (int ni = 0; ni < 4; ++ni) { p[ni] = __expf(acc[mi][ni][r] - m); s += p[ni]; }
            s = xsum4(s);                     // denom over 64 l
            float rv = 1.0f / s;
#pragma unroll
            for (int ni = 0; ni < 4; ++ni) score_l[ni] = fmaxf(score_l[ni], p[ni] * rv);
        }
    float tot = 0.f;
#pragma unroll
    for (int ni = 0; ni < 4; ++ni) {
        float v = score_l[ni];                // fold max over c across quads
        v = fmaxf(v, __shfl_xor(v, 16));
        v = fmaxf(v, __shfl_xor(v, 32));
        tot += v;
    }
    tot = xsum4(tot);                         // sum over the 16 ln-columns
    if (lane == 0) wsScr[b * T_ + t] = tot;
}

// ---------------- K3: top-5 per batch (descending, lowest-index ties) --------
__global__ void k_topn(const float* __restrict__ wsScr, int* __restrict__ wsIdx) {
    int b = blockIdx.x;
    int tid = threadIdx.x;              // 64 threads = 1 wave
    float v[4];
    for (int i = 0; i < 4; ++i) v[i] = wsScr[b * T_ + tid + 64 * i];
    for (int r = 0; r < NSEL; ++r) {
        float bv = v[0]; int bi = tid;
        for (int i = 1; i < 4; ++i) {
            int idx = tid + 64 * i;
            if (v[i] > bv) { bv = v[i]; bi = idx; }
        }
        for (int off = 32; off > 0; off >>= 1) {
            float ov = __shfl_down(bv, off);
            int   oi = __shfl_down(bi, off);
            if (ov > bv || (ov == bv && oi < bi)) { bv = ov; bi = oi; }
        }
        bi = __shfl(bi, 0);
        if (tid == 0) wsIdx[b * NSEL + r] = bi;
        if ((bi & 63) == tid) v[bi >> 6] = -1e30f;   // remove winner
    }
}

// ---------------- K4: recompute selected tiles, L2-normalize rows ------------
// One 256-thread block per (b, j); wave w computes l-columns [w*16, w*16+16).
template<bool FAST>
__global__ __launch_bounds__(256) void k_output(const int* __restrict__ targets,
                                                const float* __restrict__ emb,
                                                const _Float16* __restrict__ tab,
                                                const _Float16* __restrict__ wsA,
                                                const int* __restrict__ wsIdx,
                                                float* __restrict__ out) {
    __shared__ __align__(16) uint4 sA[A_U4];
    __shared__ float sS[LC][4];
    int b = blockIdx.y, j = blockIdx.x, tid = threadIdx.x;
    {
        const uint4* src = (const uint4*)(wsA + (size_t)b * A_HALF);
        for (int i = tid; i < A_U4; i += 256) sA[i] = src[i];
    }
    __syncthreads();

    int lane = tid & 63, wave = tid >> 6;
    int t = wsIdx[b * NSEL + j];
    const int* trow = targets + ((size_t)b * T_ + t) * LT;
    f32x4 acc[2][1];
    compute_U<FAST, 1>(sA, emb, tab, trow, wave * 16, lane, acc);

    int ln = lane & 15, quad = lane >> 4;
    // partial sum of squares over this wave's 16 l's, per c
#pragma unroll
    for (int mi = 0; mi < 2; ++mi)
#pragma unroll
        for (int r = 0; r < 4; ++r) {
            float v = acc[mi][0][r] * acc[mi][0][r];
            v = xsum4(v);                       // sum over the 16 ln-columns
            if (ln == 0) sS[mi * 16 + quad * 4 + r][wave] = v;
        }
    __syncthreads();

    float* obase = out + (size_t)(b * NSEL + j) * (LC * LT);
#pragma unroll
    for (int mi = 0; mi < 2; ++mi)
#pragma unroll
        for (int r = 0; r < 4; ++r) {
            int c = mi * 16 + quad * 4 + r;
            float ss = sS[c][0] + sS[c][1] + sS[c][2] + sS[c][3];
            float rinv = 1.0f / sqrtf(ss);
            obase[c * LT + wave * 16 + ln] = acc[mi][0][r] * rinv;
        }
}

extern "C" void kernel_launch(void* const* d_in, const int* in_sizes, int n_in,
                              void* d_out, int out_size, void* d_ws, size_t ws_size,
                              hipStream_t stream) {
    const int*   claim   = (const int*)d_in[0];
    const int*   targets = (const int*)d_in[1];
    const float* emb     = (const float*)d_in[2];
    // d_in[3] is n (=5), compile-time NSEL

    const size_t tabBytes = (size_t)VOCAB * TROW * sizeof(_Float16);   // 64 MB
    const size_t restBytes = (size_t)B_ * A_HALF * sizeof(_Float16)
                           + (size_t)B_ * T_ * sizeof(float)
                           + (size_t)B_ * NSEL * sizeof(int) + 256;
    bool fast = ws_size >= tabBytes + restBytes;   // deterministic per run

    char* p = (char*)d_ws;
    _Float16* tab = nullptr;
    if (fast) { tab = (_Float16*)p; p += tabBytes; }
    _Float16* wsA = (_Float16*)p; p += (size_t)B_ * A_HALF * sizeof(_Float16);
    float* wsScr = (float*)p;     p += (size_t)B_ * T_ * sizeof(float);
    int*   wsIdx = (int*)p;
    float* out   = (float*)d_out;

    int tableBlocks = fast ? (VOCAB / 4) : 0;
    k_prep<<<dim3(tableBlocks + 512), dim3(256), 0, stream>>>(claim, emb, tab, wsA, tableBlocks);
    if (fast) {
        k_scores<true><<<dim3(B_ * 64), dim3(256), 0, stream>>>(targets, emb, tab, wsA, wsScr);
        k_topn<<<dim3(B_), dim3(64), 0, stream>>>(wsScr, wsIdx);
        k_output<true><<<dim3(NSEL, B_), dim3(256), 0, stream>>>(targets, emb, tab, wsA, wsIdx, out);
    } else {
        k_scores<false><<<dim3(B_ * 64), dim3(256), 0, stream>>>(targets, emb, tab, wsA, wsScr);
        k_topn<<<dim3(B_), dim3(64), 0, stream>>>(wsScr, wsIdx);
        k_output<false><<<dim3(NSEL, B_), dim3(256), 0, stream>>>(targets, emb, tab, wsA, wsIdx, out);
    }
}